// Round 5
// baseline (114.973 us; speedup 1.0000x reference)
//
#include <hip/hip_runtime.h>
#include <math.h>

#define NCLASS 100
#define NSEG 30
#define F4_PER_ROW 25            // 100 floats = 25 float4, row-aligned
#define ROWS_PER_GRP 16
#define F4_PER_GRP (F4_PER_ROW * ROWS_PER_GRP)   // 400

__device__ __forceinline__ float e4(float4 v) {
    return __expf(v.x) + __expf(v.y) + __expf(v.z) + __expf(v.w);
}

// Stage group g's data into registers F0..F6 / T / S (F6 only lanes 0..15).
#define STAGE(F0,F1,F2,F3,F4V,F5,F6,T,S,g)                                  \
    do {                                                                    \
        const float4* g4_ = (const float4*)logits + (size_t)(g) * F4_PER_GRP; \
        F0 = g4_[lane      ];                                               \
        F1 = g4_[lane + 64 ];                                               \
        F2 = g4_[lane + 128];                                               \
        F3 = g4_[lane + 192];                                               \
        F4V= g4_[lane + 256];                                               \
        F5 = g4_[lane + 320];                                               \
        if (lane < 16) F6 = g4_[lane + 384];                                \
        T = target[(g) * ROWS_PER_GRP + q];                                 \
        S = seg   [(g) * ROWS_PER_GRP + q];                                 \
    } while (0)

// ---------------------------------------------------------------------------
// Kernel 1: fused CE partial sum + per-segment label histogram.
// Fully-coalesced 1024B loads + per-wave LDS bounce for the row reduction,
// now 2-deep software pipelined: group g+1's loads are issued before group
// g's compute, and the x[target] gather (L2-hot) is issued at the top of the
// compute phase so its latency hides under the exp block.
// ---------------------------------------------------------------------------
__global__ __launch_bounds__(256) void ce_hist_kernel(
    const float* __restrict__ logits,   // [N, 100]
    const int*   __restrict__ target,   // [N]
    const int*   __restrict__ seg,      // [N]
    int N,
    int*    __restrict__ g_counts,      // [n_rep][NSEG*NCLASS]
    int n_rep,
    double* __restrict__ g_loss)        // [1]
{
    __shared__ int    lds_hist[NSEG * NCLASS];   // 12 KB
    __shared__ float  part[4][F4_PER_GRP];       // 6.4 KB (per-wave slices)
    __shared__ double lds_loss[4];

    for (int i = threadIdx.x; i < NSEG * NCLASS; i += blockDim.x) lds_hist[i] = 0;
    __syncthreads();

    const int lane          = threadIdx.x & 63;
    const int wv            = threadIdx.x >> 6;
    const int sub           = lane & 3;     // quad sub-index (reduce pass)
    const int q             = lane >> 2;    // row within group (reduce pass)
    const int wavesPerBlock = blockDim.x >> 6;
    const int gwave         = blockIdx.x * wavesPerBlock + wv;
    const int totWaves      = gridDim.x * wavesPerBlock;
    const int ngroups       = N >> 4;       // N % 16 == 0

    double acc = 0.0;
    const float NEG = -INFINITY;

    int  gA    = gwave;
    bool haveA = (gA < ngroups);

    float4 A0, A1, A2, A3, A4, A5, A6;
    A6 = make_float4(NEG, NEG, NEG, NEG);
    int tA = 0, sA = 0;
    if (haveA) STAGE(A0, A1, A2, A3, A4, A5, A6, tA, sA, gA);

    while (haveA) {
        const int  gB    = gA + totWaves;
        const bool haveB = (gB < ngroups);

        // ---- prefetch next group's payload ----
        float4 B0, B1, B2, B3, B4, B5, B6;
        B6 = make_float4(NEG, NEG, NEG, NEG);
        int tB = 0, sB = 0;
        if (haveB) STAGE(B0, B1, B2, B3, B4, B5, B6, tB, sB, gB);

        // ---- issue x[target] gather for current group (lines are L2-hot) ----
        const float xt = logits[(size_t)(gA * ROWS_PER_GRP + q) * NCLASS + tA];

        // ---- exp partials -> LDS bounce ----
        part[wv][lane      ] = e4(A0);
        part[wv][lane + 64 ] = e4(A1);
        part[wv][lane + 128] = e4(A2);
        part[wv][lane + 192] = e4(A3);
        part[wv][lane + 256] = e4(A4);
        part[wv][lane + 320] = e4(A5);
        if (lane < 16) part[wv][lane + 384] = e4(A6);

        // ---- quad-per-row gather of 25 partials ----
        const int base = F4_PER_ROW * q + sub;
        float e = part[wv][base     ] + part[wv][base + 4 ] + part[wv][base + 8 ]
                + part[wv][base + 12] + part[wv][base + 16] + part[wv][base + 20];
        if (sub == 0) e += part[wv][F4_PER_ROW * q + 24];
        e += __shfl_xor(e, 1);
        e += __shfl_xor(e, 2);

        if (sub == 0) {
            acc += (double)(__logf(e) - xt);
            atomicAdd(&lds_hist[sA * NCLASS + tA], 1);
        }

        // ---- rotate pipeline ----
        A0 = B0; A1 = B1; A2 = B2; A3 = B3; A4 = B4; A5 = B5; A6 = B6;
        tA = tB; sA = sB;
        gA = gB; haveA = haveB;
    }

    // full-wave sum of acc (nonzero only on sub==0 lanes)
    #pragma unroll
    for (int off = 32; off; off >>= 1) acc += __shfl_xor(acc, off);
    if (lane == 0) lds_loss[wv] = acc;
    __syncthreads();                 // also fences LDS hist atomics

    if (threadIdx.x == 0) {
        double b = 0.0;
        for (int w = 0; w < wavesPerBlock; ++w) b += lds_loss[w];
        atomicAdd(g_loss, b);
    }
    int* my_counts = g_counts + (size_t)(blockIdx.x & (n_rep - 1)) * (NSEG * NCLASS);
    for (int i = threadIdx.x; i < NSEG * NCLASS; i += blockDim.x) {
        int c = lds_hist[i];
        if (c) atomicAdd(&my_counts[i], c);
    }
}

// ---------------------------------------------------------------------------
// Kernel 2: parallel per-segment argmax + loss finalize.
// 8 threads per segment; packed key (count<<7)|(127-c): max-key == first-max
// (jnp.argmax tie rule: equal counts -> smaller class id wins).
// ---------------------------------------------------------------------------
__global__ void finalize_kernel(
    const int* __restrict__ g_counts,
    int n_rep,
    const double* __restrict__ g_loss,
    int N,
    int* __restrict__ g_mode,
    float* __restrict__ out_loss)
{
    const int t = threadIdx.x;        // 256 threads
    const int s = t >> 3;             // segment
    const int j = t & 7;
    if (s < NSEG) {
        int bestKey = -1;
        for (int c = j; c < NCLASS; c += 8) {
            int v = 0;
            for (int r = 0; r < n_rep; ++r)
                v += g_counts[r * (NSEG * NCLASS) + s * NCLASS + c];
            int key = (v << 7) | (127 - c);
            bestKey = max(bestKey, key);
        }
        bestKey = max(bestKey, __shfl_xor(bestKey, 1));
        bestKey = max(bestKey, __shfl_xor(bestKey, 2));
        bestKey = max(bestKey, __shfl_xor(bestKey, 4));
        if (j == 0) g_mode[s] = 127 - (bestKey & 127);
    }
    if (t == 0) out_loss[0] = (float)(g_loss[0] / (double)N);
}

// ---------------------------------------------------------------------------
// Kernel 3: relabeled[i] = mode[seg[i]] written as fp32
// ---------------------------------------------------------------------------
__global__ __launch_bounds__(256) void relabel_kernel(
    const int* __restrict__ seg,
    const int* __restrict__ g_mode,
    float* __restrict__ out,
    int N)
{
    __shared__ float mode_f[NSEG];
    for (int i = threadIdx.x; i < NSEG; i += blockDim.x)
        mode_f[i] = (float)g_mode[i];
    __syncthreads();

    int idx    = blockIdx.x * blockDim.x + threadIdx.x;
    int stride = gridDim.x * blockDim.x;
    for (int i = idx; i < N; i += stride)
        out[i] = mode_f[seg[i]];
}

// ---------------------------------------------------------------------------
extern "C" void kernel_launch(void* const* d_in, const int* in_sizes, int n_in,
                              void* d_out, int out_size, void* d_ws, size_t ws_size,
                              hipStream_t stream)
{
    const float* logits = (const float*)d_in[0];
    const int*   target = (const int*)d_in[1];
    const int*   seg    = (const int*)d_in[2];
    float* out = (float*)d_out;

    const int N = in_sizes[1];          // N_PIXELS (2^20, divisible by 16)

    // counts replication to spread atomic contention (power of 2)
    int n_rep = 8;
    size_t need = 16 + (size_t)n_rep * NSEG * NCLASS * sizeof(int) + 128;
    if (ws_size < need) n_rep = 1;

    // workspace: [0..7] double loss_sum, [16..] counts[n_rep][3000], then mode[30]
    double* g_loss   = (double*)d_ws;
    int*    g_counts = (int*)((char*)d_ws + 16);
    int*    g_mode   = (int*)((char*)d_ws + 16 + (size_t)n_rep * NSEG * NCLASS * sizeof(int));

    hipMemsetAsync(d_ws, 0, 16 + (size_t)n_rep * NSEG * NCLASS * sizeof(int), stream);

    ce_hist_kernel<<<2048, 256, 0, stream>>>(logits, target, seg, N, g_counts, n_rep, g_loss);
    finalize_kernel<<<1, 256, 0, stream>>>(g_counts, n_rep, g_loss, N, g_mode, out);
    relabel_kernel<<<1024, 256, 0, stream>>>(seg, g_mode, out + 1, N);
}